// Round 10
// baseline (523.386 us; speedup 1.0000x reference)
//
#include <hip/hip_runtime.h>
#include <math.h>

#define PP 8192
#define DD 4096
#define NTOT 32768           // B * P
#define K_LOW 29490          // floor(0.9 * (NTOT-1))
#define NBINS 8192           // bucket = bits(|a|) >> 18
#define SCALE 1048576.0f     // 2^20 fixed-point for spmv accumulation
#define INV_SCALE (1.0f / 1048576.0f)
#define MSCALE 262144.0f     // 2^18 fixed-point for mean-sum accumulation
#define INV_MSCALE (1.0f / 262144.0f)
#define LIST_CAP 3072
#define NBLK 256
#define NTHR 1024

__device__ __forceinline__ float dot4(float4 w, float4 v) {
  return fmaf(w.x, v.x, fmaf(w.y, v.y, fmaf(w.z, v.z, w.w * v.w)));
}

struct ThrS {
  unsigned h[NBINS];         // 32 KB (phase 1a hist for blocks 0-7)
  unsigned scan[NTHR];       // 4 KB
  unsigned list1[LIST_CAP];  // 12 KB
  unsigned list2[LIST_CAP];  // 12 KB
  unsigned n1, n2, b1, r1, b2, r2, vlo, vhi;
};
struct SpmvS {
  float st[PP];              // 32 KB
  int   rc[PP];              // 32 KB
};
union FusedS {
  ThrS t;
  SpmvS s;
};

// Device-scope grid barrier, RMW-spin-free (R9 lesson: atomicAdd(cnt,0) spin
// from 256 blocks serializes the coherence point -> ~180us/barrier).
// Arrival: one fetch_add(RELEASE, agent). Spin: plain agent-scope atomic LOAD
// (no RMW; concurrent reads of one line don't serialize) + s_sleep backoff.
// Whole grid co-resident: 256 blocks x 1024 thr, 64.5 KB LDS -> 1 block/CU.
__device__ __forceinline__ void grid_barrier(unsigned* cnt, unsigned target) {
  __threadfence();
  __syncthreads();
  if (threadIdx.x == 0) {
    __hip_atomic_fetch_add(cnt, 1u, __ATOMIC_RELEASE, __HIP_MEMORY_SCOPE_AGENT);
    while (__hip_atomic_load(cnt, __ATOMIC_RELAXED, __HIP_MEMORY_SCOPE_AGENT) < target)
      __builtin_amdgcn_s_sleep(10);
  }
  __syncthreads();
  __threadfence();
}

__global__ __launch_bounds__(NTHR) void fused_kernel(
    const float* __restrict__ x, const float* __restrict__ W,
    const float* __restrict__ bias, const float* __restrict__ vals,
    const int* __restrict__ rows, const int* __restrict__ cols,
    const float* __restrict__ sstate, float* __restrict__ a,
    unsigned* __restrict__ hist, int* __restrict__ rec,
    int* __restrict__ acc, unsigned* __restrict__ bar,
    float* __restrict__ out, int nc) {
  __shared__ FusedS sh;
  const int tid = threadIdx.x;
  const int blk = blockIdx.x;
  const int lane = tid & 63;
  const int wave = tid >> 6;

  // ---------- phase 0a: zero aux (consumed only after barrier 1) ----------
  if (blk < 8) rec[blk * NTHR + tid] = 0;
  else if (blk < 16) hist[(blk - 8) * NTHR + tid] = 0u;
  else if (blk == 16 && tid < 4) acc[tid] = 0;

  // ---------- phase 0b: gemm, 2 rows/wave (proven shape, bit-identical a) ----------
  {
    const int p0 = blk * 32 + wave * 2;
    const float4* __restrict__ W0 = (const float4*)(W + (size_t)p0 * DD);
    const float4* __restrict__ W1 = W0 + (DD / 4);
    const float4* __restrict__ x4 = (const float4*)x;
    double a00 = 0.0, a01 = 0.0, a02 = 0.0, a03 = 0.0;
    double a10 = 0.0, a11 = 0.0, a12 = 0.0, a13 = 0.0;
    #pragma unroll 4
    for (int k = 0; k < 16; ++k) {
      const int i = lane + k * 64;
      float4 w0 = W0[i];
      float4 w1 = W1[i];
      float4 v0 = x4[i];
      float4 v1 = x4[1024 + i];
      float4 v2 = x4[2048 + i];
      float4 v3 = x4[3072 + i];
      a00 += (double)dot4(w0, v0);
      a01 += (double)dot4(w0, v1);
      a02 += (double)dot4(w0, v2);
      a03 += (double)dot4(w0, v3);
      a10 += (double)dot4(w1, v0);
      a11 += (double)dot4(w1, v1);
      a12 += (double)dot4(w1, v2);
      a13 += (double)dot4(w1, v3);
    }
    #pragma unroll
    for (int off = 32; off > 0; off >>= 1) {
      a00 += __shfl_down(a00, off);
      a01 += __shfl_down(a01, off);
      a02 += __shfl_down(a02, off);
      a03 += __shfl_down(a03, off);
      a10 += __shfl_down(a10, off);
      a11 += __shfl_down(a11, off);
      a12 += __shfl_down(a12, off);
      a13 += __shfl_down(a13, off);
    }
    if (lane == 0) {
      float b0 = bias[p0];
      float b1 = bias[p0 + 1];
      a[0 * PP + p0] = (float)a00 + b0;
      a[1 * PP + p0] = (float)a01 + b0;
      a[2 * PP + p0] = (float)a02 + b0;
      a[3 * PP + p0] = (float)a03 + b0;
      a[0 * PP + p0 + 1] = (float)a10 + b1;
      a[1 * PP + p0 + 1] = (float)a11 + b1;
      a[2 * PP + p0 + 1] = (float)a12 + b1;
      a[3 * PP + p0 + 1] = (float)a13 + b1;
    }
  }

  // ---------- phase 0c: stream own COO slice into L3 (read again in phase 2) ----------
  const int quads = nc >> 2;
  const int per = (quads + NBLK - 1) / NBLK;
  const int lo = blk * per;
  const int hi = min(lo + per, quads);
  {
    const float4* __restrict__ v4 = (const float4*)vals;
    const int4* __restrict__ r4 = (const int4*)rows;
    const int4* __restrict__ c4 = (const int4*)cols;
    float fs = 0.0f;
    int is = 0;
    for (int i = lo + tid; i < hi; i += NTHR) {
      float4 v = v4[i];
      int4 r = r4[i];
      int4 c = c4[i];
      fs += v.x + v.y + v.z + v.w;
      is += r.x + r.y + r.z + r.w + c.x + c.y + c.z + c.w;
    }
    asm volatile("" :: "v"(fs), "v"(is));  // keep loads live
  }

  grid_barrier(bar, NBLK);  // a complete, aux zeroed, COO warm

  // ---------- phase 1a: hist (blocks 0-7, LDS ds_add, spread global merge) ----------
  if (blk < 8) {
    #pragma unroll
    for (int j = 0; j < NBINS / NTHR; ++j) sh.t.h[tid + j * NTHR] = 0u;
    __syncthreads();
    const int base = blk * 4096 + tid;
    #pragma unroll
    for (int k = 0; k < 4; ++k) {
      unsigned u = __float_as_uint(fabsf(a[base + k * 1024]));
      atomicAdd(&sh.t.h[u >> 18], 1u);
    }
    __syncthreads();
    #pragma unroll
    for (int j = 0; j < NBINS / NTHR; ++j) {
      unsigned c = sh.t.h[tid + j * NTHR];
      if (c) atomicAdd(&hist[tid + j * NTHR], c);
    }
  }

  grid_barrier(bar, 2u * NBLK);  // hist complete

  // ---------- phase 1b: exact 0.9-quantile (redundant per block, deterministic) ----------
  float thr_v;
  {
    const uint4* h4 = (const uint4*)hist;
    uint4 q0 = h4[tid * 2];
    uint4 q1 = h4[tid * 2 + 1];
    unsigned part = q0.x + q0.y + q0.z + q0.w + q1.x + q1.y + q1.z + q1.w;
    sh.t.scan[tid] = part;
    if (tid == 0) { sh.t.n1 = 0; sh.t.n2 = 0; }
    __syncthreads();
    for (int off = 1; off < NTHR; off <<= 1) {
      unsigned v = (tid >= off) ? sh.t.scan[tid - off] : 0u;
      __syncthreads();
      sh.t.scan[tid] += v;
      __syncthreads();
    }
    const unsigned incl = sh.t.scan[tid];
    const unsigned excl = incl - part;
    unsigned bins[8] = {q0.x, q0.y, q0.z, q0.w, q1.x, q1.y, q1.z, q1.w};
    if (excl <= (unsigned)K_LOW && (unsigned)K_LOW < incl) {
      unsigned r = (unsigned)K_LOW - excl, cum = 0;
      #pragma unroll
      for (int j = 0; j < 8; ++j) {
        if (cum + bins[j] > r) { sh.t.b1 = tid * 8 + j; sh.t.r1 = r - cum; break; }
        cum += bins[j];
      }
    }
    if (excl <= (unsigned)(K_LOW + 1) && (unsigned)(K_LOW + 1) < incl) {
      unsigned r = (unsigned)(K_LOW + 1) - excl, cum = 0;
      #pragma unroll
      for (int j = 0; j < 8; ++j) {
        if (cum + bins[j] > r) { sh.t.b2 = tid * 8 + j; sh.t.r2 = r - cum; break; }
        cum += bins[j];
      }
    }
    __syncthreads();
    const unsigned b1 = sh.t.b1, r1 = sh.t.r1, b2 = sh.t.b2, r2 = sh.t.r2;
    for (int i = tid; i < NTOT; i += NTHR) {
      unsigned u = __float_as_uint(fabsf(a[i]));
      unsigned bk = u >> 18;
      if (bk == b1) {
        unsigned idx = atomicAdd(&sh.t.n1, 1u);
        if (idx < LIST_CAP) sh.t.list1[idx] = u;
      } else if (bk == b2) {
        unsigned idx = atomicAdd(&sh.t.n2, 1u);
        if (idx < LIST_CAP) sh.t.list2[idx] = u;
      }
    }
    __syncthreads();
    const unsigned m1 = min(sh.t.n1, (unsigned)LIST_CAP);
    const unsigned m2 = min(sh.t.n2, (unsigned)LIST_CAP);
    for (unsigned i = tid; i < m1; i += NTHR) {
      unsigned ui = sh.t.list1[i];
      unsigned ltc = 0, eqb = 0;
      for (unsigned j = 0; j < m1; ++j) {
        unsigned uj = sh.t.list1[j];
        ltc += (uj < ui) ? 1u : 0u;
        eqb += ((uj == ui) && (j < i)) ? 1u : 0u;
      }
      unsigned rk = ltc + eqb;
      if (rk == r1) sh.t.vlo = ui;
      if (b2 == b1 && rk == r2) sh.t.vhi = ui;
    }
    if (b2 != b1) {
      for (unsigned i = tid; i < m2; i += NTHR) {
        unsigned ui = sh.t.list2[i];
        unsigned ltc = 0, eqb = 0;
        for (unsigned j = 0; j < m2; ++j) {
          unsigned uj = sh.t.list2[j];
          ltc += (uj < ui) ? 1u : 0u;
          eqb += ((uj == ui) && (j < i)) ? 1u : 0u;
        }
        if (ltc + eqb == r2) sh.t.vhi = ui;
      }
    }
    __syncthreads();
    const double dlo = (double)__uint_as_float(sh.t.vlo);
    const double dhi = (double)__uint_as_float(sh.t.vhi);
    const double idxq = 0.9 * (double)(NTOT - 1);
    const double gq = idxq - floor(idxq);
    thr_v = (float)(dlo + gq * (dhi - dlo));
    __syncthreads();  // release thr-phase LDS before union reuse
  }

  // ---------- phase 2: COO SpMV over own (L3-warm) slice ----------
  {
    for (int i = tid; i < PP; i += NTHR) {
      float a0 = a[i];
      sh.s.st[i] = (fabsf(a0) > thr_v) ? a0 : 0.9f * sstate[i];
      sh.s.rc[i] = 0;
    }
    __syncthreads();
    const float4* __restrict__ v4 = (const float4*)vals;
    const int4* __restrict__ r4 = (const int4*)rows;
    const int4* __restrict__ c4 = (const int4*)cols;
    for (int i = lo + tid; i < hi; i += NTHR) {
      float4 v = v4[i];
      int4 r = r4[i];
      int4 c = c4[i];
      atomicAdd((unsigned*)&sh.s.rc[r.x], (unsigned)__float2int_rn(v.x * sh.s.st[c.x] * SCALE));
      atomicAdd((unsigned*)&sh.s.rc[r.y], (unsigned)__float2int_rn(v.y * sh.s.st[c.y] * SCALE));
      atomicAdd((unsigned*)&sh.s.rc[r.z], (unsigned)__float2int_rn(v.z * sh.s.st[c.z] * SCALE));
      atomicAdd((unsigned*)&sh.s.rc[r.w], (unsigned)__float2int_rn(v.w * sh.s.st[c.w] * SCALE));
    }
    if (blk == 0 && tid < (nc - (quads << 2))) {
      int i = (quads << 2) + tid;
      atomicAdd((unsigned*)&sh.s.rc[rows[i]],
                (unsigned)__float2int_rn(vals[i] * sh.s.st[cols[i]] * SCALE));
    }
    __syncthreads();
    for (int i = tid; i < PP; i += NTHR)
      atomicAdd((unsigned*)&rec[i], (unsigned)sh.s.rc[i]);
  }

  grid_barrier(bar, 3u * NBLK);  // rec complete

  // ---------- phase 3: GELU + scalars (blocks 0-7, done-counter finish) ----------
  if (blk < 8) {
    __shared__ float wsum[16];
    __shared__ unsigned wcnt[16];
    const int p = blk * NTHR + tid;
    float r = (float)rec[p] * INV_SCALE;
    float a0 = a[p];
    bool m = fabsf(a0) > thr_v;
    float st = m ? a0 : 0.9f * sstate[p];
    float v = st + 0.1f * r;
    float ns = 0.5f * v * (1.0f + erff(v * 0.70710678118654752440f));
    out[p] = ns;
    float lsum = m ? ns : 0.0f;
    unsigned lcnt = m ? 1u : 0u;
    #pragma unroll
    for (int off = 32; off > 0; off >>= 1) {
      lsum += __shfl_down(lsum, off);
      lcnt += __shfl_down(lcnt, off);
    }
    if (lane == 0) { wsum[wave] = lsum; wcnt[wave] = lcnt; }
    __syncthreads();
    if (tid == 0) {
      float bsum = 0.0f;
      unsigned bcnt = 0;
      #pragma unroll
      for (int w = 0; w < 16; ++w) { bsum += wsum[w]; bcnt += wcnt[w]; }
      atomicAdd((unsigned*)&acc[0], (unsigned)__float2int_rn(bsum * MSCALE));
      atomicAdd((unsigned*)&acc[1], bcnt);
      __threadfence();
      unsigned d = atomicAdd((unsigned*)&acc[2], 1u);
      if (d == 7u) {
        int sfix = (int)atomicAdd((unsigned*)&acc[0], 0u);
        int cnt = (int)atomicAdd((unsigned*)&acc[1], 0u);
        out[PP] = (float)cnt;
        out[PP + 1] = (cnt > 0) ? ((float)sfix * INV_MSCALE / (float)cnt) : 0.0f;
      }
    }
  }
}

extern "C" void kernel_launch(void* const* d_in, const int* in_sizes, int n_in,
                              void* d_out, int out_size, void* d_ws, size_t ws_size,
                              hipStream_t stream) {
  const float* x      = (const float*)d_in[0];
  const float* W      = (const float*)d_in[1];
  const float* bias   = (const float*)d_in[2];
  const float* vals   = (const float*)d_in[3];
  const float* sstate = (const float*)d_in[4];
  const int*   rows   = (const int*)d_in[5];
  const int*   cols   = (const int*)d_in[6];
  const int    nc     = in_sizes[3];
  float* out = (float*)d_out;
  float* ws  = (float*)d_ws;

  float*    a    = ws;                              // 32768 floats
  unsigned* hist = (unsigned*)(ws + 32768);         // 8192 bins
  int*      rec  = (int*)(ws + 32768 + NBINS);      // 8192 ints
  int*      acc  = (int*)(ws + 32768 + NBINS + PP); // 4 ints
  unsigned* bar  = (unsigned*)(ws + 32768 + NBINS + PP + 4);  // barrier counter

  hipMemsetAsync(bar, 0, 4 * sizeof(unsigned), stream);
  fused_kernel<<<NBLK, NTHR, 0, stream>>>(x, W, bias, vals, rows, cols, sstate,
                                          a, hist, rec, acc, bar, out, nc);
}

// Round 11
// 85.160 us; speedup vs baseline: 6.1459x; 6.1459x over previous
//
#include <hip/hip_runtime.h>
#include <math.h>

#define PP 8192
#define DD 4096
#define NTOT 32768           // B * P
#define K_LOW 29490          // floor(0.9 * (NTOT-1))
#define NBINS 8192           // bucket = bits(|a|) >> 18
#define SCALE 1048576.0f     // 2^20 fixed-point for spmv accumulation
#define INV_SCALE (1.0f / 1048576.0f)
#define MSCALE 262144.0f     // 2^18 fixed-point for mean-sum accumulation
#define INV_MSCALE (1.0f / 262144.0f)
#define LIST_CAP 3072

__device__ __forceinline__ float dot4(float4 w, float4 v) {
  return fmaf(w.x, v.x, fmaf(w.y, v.y, fmaf(w.z, v.z, w.w * v.w)));
}

// ---------------- Kernel 1: a = x @ W^T + b (R4-proven shape) ----------------
// 1024 blocks x 256 thr, 2 rows/wave, LB(256,4) -> 128-VGPR budget for deep
// MLP (R10 lesson: 1024-thr fusion caps VGPR at 64 and strangles this loop).
// First 65 blocks zero hist/rec/acc (consumed only by later dispatches).
__global__ __launch_bounds__(256, 4) void gemm_kernel(const float* __restrict__ x,
                                                      const float* __restrict__ W,
                                                      const float* __restrict__ bias,
                                                      float* __restrict__ a,
                                                      unsigned* __restrict__ hist,
                                                      int* __restrict__ rec,
                                                      int* __restrict__ acc) {
  if (blockIdx.x < 32) {
    hist[blockIdx.x * 256 + threadIdx.x] = 0u;
  } else if (blockIdx.x < 64) {
    rec[(blockIdx.x - 32) * 256 + threadIdx.x] = 0;
  } else if (blockIdx.x == 64 && threadIdx.x < 4) {
    acc[threadIdx.x] = 0;
  }
  const int wave = threadIdx.x >> 6;
  const int lane = threadIdx.x & 63;
  const int p0 = blockIdx.x * 8 + wave * 2;
  const float4* __restrict__ W0 = (const float4*)(W + (size_t)p0 * DD);
  const float4* __restrict__ W1 = W0 + (DD / 4);
  const float4* __restrict__ x4 = (const float4*)x;
  double a00 = 0.0, a01 = 0.0, a02 = 0.0, a03 = 0.0;
  double a10 = 0.0, a11 = 0.0, a12 = 0.0, a13 = 0.0;
  #pragma unroll 4
  for (int k = 0; k < 16; ++k) {
    const int i = lane + k * 64;
    float4 w0 = W0[i];
    float4 w1 = W1[i];
    float4 v0 = x4[i];
    float4 v1 = x4[1024 + i];
    float4 v2 = x4[2048 + i];
    float4 v3 = x4[3072 + i];
    a00 += (double)dot4(w0, v0);
    a01 += (double)dot4(w0, v1);
    a02 += (double)dot4(w0, v2);
    a03 += (double)dot4(w0, v3);
    a10 += (double)dot4(w1, v0);
    a11 += (double)dot4(w1, v1);
    a12 += (double)dot4(w1, v2);
    a13 += (double)dot4(w1, v3);
  }
  #pragma unroll
  for (int off = 32; off > 0; off >>= 1) {
    a00 += __shfl_down(a00, off);
    a01 += __shfl_down(a01, off);
    a02 += __shfl_down(a02, off);
    a03 += __shfl_down(a03, off);
    a10 += __shfl_down(a10, off);
    a11 += __shfl_down(a11, off);
    a12 += __shfl_down(a12, off);
    a13 += __shfl_down(a13, off);
  }
  if (lane == 0) {
    float b0 = bias[p0];
    float b1 = bias[p0 + 1];
    a[0 * PP + p0] = (float)a00 + b0;
    a[1 * PP + p0] = (float)a01 + b0;
    a[2 * PP + p0] = (float)a02 + b0;
    a[3 * PP + p0] = (float)a03 + b0;
    a[0 * PP + p0 + 1] = (float)a10 + b1;
    a[1 * PP + p0 + 1] = (float)a11 + b1;
    a[2 * PP + p0 + 1] = (float)a12 + b1;
    a[3 * PP + p0 + 1] = (float)a13 + b1;
  }
}

// ---------------- Kernel 2: LDS histogram + last-block threshold select ----------------
// 8 blocks x 1024 thr. Phase A (all blocks): per-block LDS hist (ds_add),
// spread global merge (<=8 atomics per bin). Done-counter (acc[3], 8 arrivals,
// proven finalize pattern); the LAST block continues into the exact-quantile
// select (R4 thr_kernel body) -- saves a dispatch + gap.
__global__ __launch_bounds__(1024) void hist_thr_kernel(const float* __restrict__ a,
                                                        unsigned* __restrict__ hist,
                                                        int* __restrict__ acc,
                                                        float* __restrict__ thr) {
  __shared__ union {
    unsigned h[NBINS];  // 32 KB, phase A
    struct {
      unsigned scan[1024];
      unsigned list1[LIST_CAP];
      unsigned list2[LIST_CAP];
      unsigned n1, n2, b1, r1, b2, r2, vlo, vhi;
    } t;                // ~28.7 KB, phase B
  } sh;
  __shared__ int s_last;
  const int tid = threadIdx.x;

  // ---- phase A: histogram ----
  #pragma unroll
  for (int j = 0; j < NBINS / 1024; ++j) sh.h[tid + j * 1024] = 0u;
  __syncthreads();
  const int base = blockIdx.x * 4096 + tid;
  #pragma unroll
  for (int k = 0; k < 4; ++k) {
    unsigned u = __float_as_uint(fabsf(a[base + k * 1024]));
    atomicAdd(&sh.h[u >> 18], 1u);
  }
  __syncthreads();
  #pragma unroll
  for (int j = 0; j < NBINS / 1024; ++j) {
    unsigned c = sh.h[tid + j * 1024];
    if (c) atomicAdd(&hist[tid + j * 1024], c);
  }

  // ---- done-counter handoff ----
  __threadfence();
  __syncthreads();
  if (tid == 0) {
    unsigned d = atomicAdd((unsigned*)&acc[3], 1u);
    s_last = (d == 7u) ? 1 : 0;
  }
  __syncthreads();
  if (!s_last) return;
  __threadfence();  // acquire: other blocks' hist merges visible

  // ---- phase B: exact 0.9-quantile (R4 thr_kernel body) ----
  const uint4* h4 = (const uint4*)hist;
  uint4 q0 = h4[tid * 2];
  uint4 q1 = h4[tid * 2 + 1];
  unsigned part = q0.x + q0.y + q0.z + q0.w + q1.x + q1.y + q1.z + q1.w;
  __syncthreads();  // all lanes done reading sh.h before union reuse
  sh.t.scan[tid] = part;
  if (tid == 0) { sh.t.n1 = 0; sh.t.n2 = 0; }
  __syncthreads();
  for (int off = 1; off < 1024; off <<= 1) {
    unsigned v = (tid >= off) ? sh.t.scan[tid - off] : 0u;
    __syncthreads();
    sh.t.scan[tid] += v;
    __syncthreads();
  }
  const unsigned incl = sh.t.scan[tid];
  const unsigned excl = incl - part;
  unsigned bins[8] = {q0.x, q0.y, q0.z, q0.w, q1.x, q1.y, q1.z, q1.w};
  if (excl <= (unsigned)K_LOW && (unsigned)K_LOW < incl) {
    unsigned r = (unsigned)K_LOW - excl, cum = 0;
    #pragma unroll
    for (int j = 0; j < 8; ++j) {
      if (cum + bins[j] > r) { sh.t.b1 = tid * 8 + j; sh.t.r1 = r - cum; break; }
      cum += bins[j];
    }
  }
  if (excl <= (unsigned)(K_LOW + 1) && (unsigned)(K_LOW + 1) < incl) {
    unsigned r = (unsigned)(K_LOW + 1) - excl, cum = 0;
    #pragma unroll
    for (int j = 0; j < 8; ++j) {
      if (cum + bins[j] > r) { sh.t.b2 = tid * 8 + j; sh.t.r2 = r - cum; break; }
      cum += bins[j];
    }
  }
  __syncthreads();
  const unsigned b1 = sh.t.b1, r1 = sh.t.r1, b2 = sh.t.b2, r2 = sh.t.r2;
  for (int i = tid; i < NTOT; i += 1024) {
    unsigned u = __float_as_uint(fabsf(a[i]));
    unsigned bk = u >> 18;
    if (bk == b1) {
      unsigned idx = atomicAdd(&sh.t.n1, 1u);
      if (idx < LIST_CAP) sh.t.list1[idx] = u;
    } else if (bk == b2) {
      unsigned idx = atomicAdd(&sh.t.n2, 1u);
      if (idx < LIST_CAP) sh.t.list2[idx] = u;
    }
  }
  __syncthreads();
  const unsigned m1 = min(sh.t.n1, (unsigned)LIST_CAP);
  const unsigned m2 = min(sh.t.n2, (unsigned)LIST_CAP);
  for (unsigned i = tid; i < m1; i += 1024) {
    unsigned ui = sh.t.list1[i];
    unsigned ltc = 0, eqb = 0;
    for (unsigned j = 0; j < m1; ++j) {
      unsigned uj = sh.t.list1[j];
      ltc += (uj < ui) ? 1u : 0u;
      eqb += ((uj == ui) && (j < i)) ? 1u : 0u;
    }
    unsigned rk = ltc + eqb;
    if (rk == r1) sh.t.vlo = ui;
    if (b2 == b1 && rk == r2) sh.t.vhi = ui;
  }
  if (b2 != b1) {
    for (unsigned i = tid; i < m2; i += 1024) {
      unsigned ui = sh.t.list2[i];
      unsigned ltc = 0, eqb = 0;
      for (unsigned j = 0; j < m2; ++j) {
        unsigned uj = sh.t.list2[j];
        ltc += (uj < ui) ? 1u : 0u;
        eqb += ((uj == ui) && (j < i)) ? 1u : 0u;
      }
      if (ltc + eqb == r2) sh.t.vhi = ui;
    }
  }
  __syncthreads();
  if (tid == 0) {
    double dlo = (double)__uint_as_float(sh.t.vlo);
    double dhi = (double)__uint_as_float(sh.t.vhi);
    double idx = 0.9 * (double)(NTOT - 1);
    double g = idx - floor(idx);
    thr[0] = (float)(dlo + g * (dhi - dlo));
  }
}

// ---------------- Kernel 3: COO SpMV, int fixed-point LDS accum (R4-exact) ----------------
__global__ __launch_bounds__(1024) void spmv_kernel(const float* __restrict__ vals,
                                                    const int* __restrict__ rows,
                                                    const int* __restrict__ cols,
                                                    const float* __restrict__ a,
                                                    const float* __restrict__ thr,
                                                    const float* __restrict__ sstate,
                                                    int* __restrict__ rec,
                                                    int nc) {
  __shared__ float s_state[PP];
  __shared__ int s_rec[PP];
  const int tid = threadIdx.x;
  const float t = thr[0];
  for (int i = tid; i < PP; i += 1024) {
    float a0 = a[i];
    s_state[i] = (fabsf(a0) > t) ? a0 : 0.9f * sstate[i];
    s_rec[i] = 0;
  }
  __syncthreads();
  const int n4 = nc >> 2;
  const int stride = gridDim.x * 1024;
  const float4* __restrict__ v4 = (const float4*)vals;
  const int4* __restrict__ r4 = (const int4*)rows;
  const int4* __restrict__ c4 = (const int4*)cols;
  for (int i = blockIdx.x * 1024 + tid; i < n4; i += stride) {
    float4 v = v4[i];
    int4 r = r4[i];
    int4 c = c4[i];
    atomicAdd((unsigned*)&s_rec[r.x], (unsigned)__float2int_rn(v.x * s_state[c.x] * SCALE));
    atomicAdd((unsigned*)&s_rec[r.y], (unsigned)__float2int_rn(v.y * s_state[c.y] * SCALE));
    atomicAdd((unsigned*)&s_rec[r.z], (unsigned)__float2int_rn(v.z * s_state[c.z] * SCALE));
    atomicAdd((unsigned*)&s_rec[r.w], (unsigned)__float2int_rn(v.w * s_state[c.w] * SCALE));
  }
  if (blockIdx.x == 0 && tid < (nc - (n4 << 2))) {
    int i = (n4 << 2) + tid;
    atomicAdd((unsigned*)&s_rec[rows[i]],
              (unsigned)__float2int_rn(vals[i] * s_state[cols[i]] * SCALE));
  }
  __syncthreads();
  for (int i = tid; i < PP; i += 1024)
    atomicAdd((unsigned*)&rec[i], (unsigned)s_rec[i]);
}

// ---------------- Kernel 4: GELU + fused scalars (R8-exact) ----------------
__global__ __launch_bounds__(256) void finalize_kernel(const int* __restrict__ rec,
                                                       const float* __restrict__ a,
                                                       const float* __restrict__ thr,
                                                       const float* __restrict__ sstate,
                                                       float* __restrict__ out,
                                                       int* __restrict__ acc) {
  __shared__ float wsum[4];
  __shared__ unsigned wcnt[4];
  const int p = blockIdx.x * 256 + threadIdx.x;
  const float t = thr[0];
  float r = (float)rec[p] * INV_SCALE;
  float a0 = a[p];
  bool m = fabsf(a0) > t;
  float st = m ? a0 : 0.9f * sstate[p];
  float v = st + 0.1f * r;
  float ns = 0.5f * v * (1.0f + erff(v * 0.70710678118654752440f));
  out[p] = ns;
  float lsum = m ? ns : 0.0f;
  unsigned lcnt = m ? 1u : 0u;
  #pragma unroll
  for (int off = 32; off > 0; off >>= 1) {
    lsum += __shfl_down(lsum, off);
    lcnt += __shfl_down(lcnt, off);
  }
  const int lane = threadIdx.x & 63;
  const int wid = threadIdx.x >> 6;
  if (lane == 0) { wsum[wid] = lsum; wcnt[wid] = lcnt; }
  __syncthreads();
  if (threadIdx.x == 0) {
    float bsum = wsum[0] + wsum[1] + wsum[2] + wsum[3];
    unsigned bcnt = wcnt[0] + wcnt[1] + wcnt[2] + wcnt[3];
    atomicAdd((unsigned*)&acc[0], (unsigned)__float2int_rn(bsum * MSCALE));
    atomicAdd((unsigned*)&acc[1], bcnt);
    __threadfence();
    unsigned d = atomicAdd((unsigned*)&acc[2], 1u);
    if (d == (unsigned)(gridDim.x - 1)) {
      int sfix = (int)atomicAdd((unsigned*)&acc[0], 0u);
      int cnt = (int)atomicAdd((unsigned*)&acc[1], 0u);
      out[PP] = (float)cnt;
      out[PP + 1] = (cnt > 0) ? ((float)sfix * INV_MSCALE / (float)cnt) : 0.0f;
    }
  }
}

extern "C" void kernel_launch(void* const* d_in, const int* in_sizes, int n_in,
                              void* d_out, int out_size, void* d_ws, size_t ws_size,
                              hipStream_t stream) {
  const float* x      = (const float*)d_in[0];
  const float* W      = (const float*)d_in[1];
  const float* bias   = (const float*)d_in[2];
  const float* vals   = (const float*)d_in[3];
  const float* sstate = (const float*)d_in[4];
  const int*   rows   = (const int*)d_in[5];
  const int*   cols   = (const int*)d_in[6];
  const int    nc     = in_sizes[3];
  float* out = (float*)d_out;
  float* ws  = (float*)d_ws;

  float*    a    = ws;                              // 32768 floats
  float*    thr  = ws + 32768;                      // 16 floats
  unsigned* hist = (unsigned*)(ws + 32784);         // 8192 bins
  int*      rec  = (int*)(ws + 32784 + NBINS);      // 8192 ints
  int*      acc  = (int*)(ws + 32784 + NBINS + PP); // 4 ints (sum, cnt, done, hist-done)

  gemm_kernel<<<PP / 8, 256, 0, stream>>>(x, W, bias, a, hist, rec, acc);
  hist_thr_kernel<<<NTOT / 4096, 1024, 0, stream>>>(a, hist, acc, thr);
  spmv_kernel<<<256, 1024, 0, stream>>>(vals, rows, cols, a, thr, sstate, rec, nc);
  finalize_kernel<<<PP / 256, 256, 0, stream>>>(rec, a, thr, sstate, out, acc);
}